// Round 6
// baseline (377.579 us; speedup 1.0000x reference)
//
#include <hip/hip_runtime.h>
#include <math.h>

#define NB 2048
#define LL 200
#define DD 64
#define CC 9
#define HH 16
#define NW 4

// ---- d_ws layout (bytes) ----
// srow_g : int  [B*L]   @ 0          (1,638,400)
// z_g    : float[B*L]   @ 1,638,400  (1,638,400)   z = exp(s), M=0 softmax
// cstart : int  [B*10]  @ 3,276,800  (81,920)

// K1: per-user ballot sort + per-item MLP score -> z = exp(s)
__global__ __launch_bounds__(256, 6) void din_k1(
    const int* __restrict__ user_inputs,
    const int* __restrict__ record_inputs,
    const int* __restrict__ item_cat,
    const float* __restrict__ user_emb,
    const float* __restrict__ item_emb,
    const float* __restrict__ W1,
    const float* __restrict__ b1,
    const float* __restrict__ W2,
    const float* __restrict__ b2,
    int* __restrict__ srow_g,
    float* __restrict__ z_g,
    int* __restrict__ cstart_g)
{
  const int b = blockIdx.x;
  const int t = threadIdx.x;
  const int wave = t >> 6, lane = t & 63;

  __shared__ float u_s[DD];
  __shared__ float pre_s[CC][HH];
  __shared__ int   wcnt[NW][CC];
  __shared__ int   cstart[CC + 1];
  __shared__ int   srow_sh[LL];

  // loads + ballot counting
  int r = -1, c0 = -1;
  if (t < LL) {
    r = record_inputs[b * LL + t];
    if (r >= 0) c0 = item_cat[r];
  }
  if (t < DD) u_s[t] = user_emb[(size_t)user_inputs[b] * DD + t];

  int myrank = 0;
  #pragma unroll
  for (int c = 0; c < CC; ++c) {
    unsigned long long m = __ballot(c0 == c);
    if (lane == 0) wcnt[wave][c] = __popcll(m);
    if (c0 == c) myrank = __popcll(m & ((1ULL << lane) - 1ULL));
  }
  __syncthreads();

  if (t == 0) {
    int acc = 0;
    #pragma unroll
    for (int c = 0; c < CC; ++c) {
      cstart[c] = acc;
      acc += wcnt[0][c] + wcnt[1][c] + wcnt[2][c] + wcnt[3][c];
    }
    cstart[CC] = acc;
  }
  if (t < CC * HH) {   // pre = b1 + W1u . u
    int c = t / HH, j = t % HH;
    const float* wp = &W1[(size_t)(c * HH + j) * (2 * DD)];
    float acc = b1[c * HH + j];
    #pragma unroll 8
    for (int d = 0; d < DD; ++d) acc += wp[d] * u_s[d];
    pre_s[c][j] = acc;
  }
  __syncthreads();

  // stable scatter (to LDS + global for K2)
  if (c0 >= 0) {
    int off = cstart[c0];
    for (int w = 0; w < wave; ++w) off += wcnt[w][c0];
    int pos = off + myrank;
    srow_sh[pos] = r;
    srow_g[b * LL + pos] = r;
  }
  if (t < CC + 1) cstart_g[b * 10 + t] = cstart[t];
  __syncthreads();

  const int nvalid = cstart[CC];

  // per-item MLP score: e loaded once (i-outer / j-inner), z = exp(s)
  if (t < nvalid) {
    int c = 0;
    #pragma unroll
    for (int q = 0; q < CC - 1; ++q) c += (t >= cstart[q + 1]) ? 1 : 0;
    int row = srow_sh[t];
    const float4* ep = (const float4*)&item_emb[(size_t)row * DD];
    const float4* wbase = (const float4*)&W1[(size_t)c * HH * (2 * DD) + DD];

    float acc[HH];
    #pragma unroll
    for (int j = 0; j < HH; ++j) acc[j] = pre_s[c][j];

    #pragma unroll
    for (int i = 0; i < 16; ++i) {
      float4 ev = ep[i];
      #pragma unroll
      for (int j = 0; j < HH; ++j) {
        float4 wv = wbase[j * 32 + i];
        acc[j] += wv.x * ev.x + wv.y * ev.y + wv.z * ev.z + wv.w * ev.w;
      }
    }
    float s = b2[c];
    #pragma unroll
    for (int j = 0; j < HH; ++j) s += W2[c * HH + j] * fmaxf(acc[j], 0.f);
    z_g[b * LL + t] = expf(s);
  }
}

// K2: 9 waves per user (wave = category): gvec + top attention + output
__global__ __launch_bounds__(576) void din_k2(
    const int* __restrict__ user_inputs,
    const int* __restrict__ item_inputs,
    const float* __restrict__ user_emb,
    const float* __restrict__ item_emb,
    const float* __restrict__ Wt1,
    const float* __restrict__ bt1,
    const float* __restrict__ Wt2,
    const float* __restrict__ bt2,
    const int* __restrict__ srow_g,
    const float* __restrict__ z_g,
    const int* __restrict__ cstart_g,
    float* __restrict__ out)
{
  const int b = blockIdx.x;
  const int t = threadIdx.x;
  const int wave = t >> 6, lane = t & 63;   // wave == category

  __shared__ int   cstart_s[CC + 1];
  __shared__ float u_s[DD];
  __shared__ float gvec_s[CC][DD];
  __shared__ float h2_s[CC][HH];
  __shared__ float w2_s[CC];

  if (t < CC + 1) cstart_s[t] = cstart_g[b * 10 + t];
  if (t >= 64 && t < 128) u_s[t - 64] = user_emb[(size_t)user_inputs[b] * DD + (t - 64)];
  __syncthreads();

  // ---- per-wave: softmax-normalized weighted sum for category c = wave ----
  {
    const int c = wave;
    const int i0 = cstart_s[c], i1 = cstart_s[c + 1];
    const int base = b * LL;

    float zs = 0.f;
    for (int i = i0 + lane; i < i1; i += 64) zs += z_g[base + i];
    #pragma unroll
    for (int off = 32; off > 0; off >>= 1) zs += __shfl_xor(zs, off, 64);
    const float inv = 1.f / fmaxf(zs, 1e-30f);

    float acc = 0.f;
    if (i1 > i0) {
      int row = srow_g[base + i0];
      float ev = item_emb[(size_t)row * DD + lane];
      for (int i = i0; i < i1; ++i) {
        float ec = ev;
        if (i + 1 < i1) {               // prefetch next row
          int r2 = srow_g[base + i + 1];
          ev = item_emb[(size_t)r2 * DD + lane];
        }
        acc += z_g[base + i] * ec;
      }
    }
    gvec_s[c][lane] = acc * inv;        // empty cat -> 0
  }
  __syncthreads();

  // ---- top-level attention ----
  if (t < CC * HH) {
    int c = t / HH, j = t % HH;
    const float* wp = &Wt1[(size_t)j * (2 * DD)];
    float acc = bt1[j];
    #pragma unroll 8
    for (int d = 0; d < DD; ++d) acc += wp[d] * u_s[d];
    #pragma unroll 8
    for (int d = 0; d < DD; ++d) acc += wp[DD + d] * gvec_s[c][d];
    h2_s[c][j] = fmaxf(acc, 0.f);
  }
  __syncthreads();

  if (t == 0) {
    float s2[CC];
    float m = -INFINITY;
    #pragma unroll
    for (int c = 0; c < CC; ++c) {
      float acc = bt2[0];
      #pragma unroll
      for (int j = 0; j < HH; ++j) acc += Wt2[j] * h2_s[c][j];
      s2[c] = acc;
      if (cstart_s[c + 1] > cstart_s[c]) m = fmaxf(m, acc);
    }
    if (m == -INFINITY) m = 0.f;
    float sum = 0.f;
    float z2[CC];
    #pragma unroll
    for (int c = 0; c < CC; ++c) {
      z2[c] = (cstart_s[c + 1] > cstart_s[c]) ? expf(s2[c] - m) : 0.f;
      sum += z2[c];
    }
    float invs = 1.f / fmaxf(sum, 1e-30f);
    #pragma unroll
    for (int c = 0; c < CC; ++c) w2_s[c] = z2[c] * invs;
  }
  __syncthreads();

  if (t < DD) {
    float hy = 0.f;
    #pragma unroll
    for (int c = 0; c < CC; ++c) hy += w2_s[c] * gvec_s[c][t];
    float ti = item_emb[(size_t)item_inputs[b] * DD + t];
    float prod = hy * ti;
    #pragma unroll
    for (int off = 32; off > 0; off >>= 1)
      prod += __shfl_down(prod, off, 64);
    if (t == 0) out[b] = prod;
  }
}

extern "C" void kernel_launch(void* const* d_in, const int* in_sizes, int n_in,
                              void* d_out, int out_size, void* d_ws, size_t ws_size,
                              hipStream_t stream) {
  const int*   user_inputs   = (const int*)d_in[0];
  const int*   record_inputs = (const int*)d_in[1];
  const int*   item_inputs   = (const int*)d_in[2];
  const int*   item_cat      = (const int*)d_in[3];
  const float* user_emb      = (const float*)d_in[4];
  const float* item_emb      = (const float*)d_in[5];
  const float* W1            = (const float*)d_in[6];
  const float* b1            = (const float*)d_in[7];
  const float* W2            = (const float*)d_in[8];
  const float* b2            = (const float*)d_in[9];
  const float* Wt1           = (const float*)d_in[10];
  const float* bt1           = (const float*)d_in[11];
  const float* Wt2           = (const float*)d_in[12];
  const float* bt2           = (const float*)d_in[13];
  float* out = (float*)d_out;

  char* ws = (char*)d_ws;
  int*   srow_g   = (int*)(ws);                 // B*L ints
  float* z_g      = (float*)(ws + 1638400);     // B*L floats
  int*   cstart_g = (int*)(ws + 3276800);       // B*10 ints

  din_k1<<<NB, 256, 0, stream>>>(user_inputs, record_inputs, item_cat,
                                 user_emb, item_emb, W1, b1, W2, b2,
                                 srow_g, z_g, cstart_g);
  din_k2<<<NB, 576, 0, stream>>>(user_inputs, item_inputs, user_emb, item_emb,
                                 Wt1, bt1, Wt2, bt2,
                                 srow_g, z_g, cstart_g, out);
}

// Round 7
// 116.707 us; speedup vs baseline: 3.2353x; 3.2353x over previous
//
#include <hip/hip_runtime.h>
#include <math.h>

#define NB 2048
#define LL 200
#define DD 64
#define CC 9
#define HH 16
#define NW 4

// ---- d_ws layout (bytes) ----
// srow_g : int  [B*L]   @ 0          (1,638,400)
// z_g    : float[B*L]   @ 1,638,400  (1,638,400)   z = exp(s), M=0 softmax
// cstart : int  [B*10]  @ 3,276,800  (81,920)

// K1: per-user ballot sort + per-item MLP score -> z = exp(s)
// W1 e-half staged in LDS as [j][i][c] float4 (broadcast for same-cat lanes,
// adjacent banks for cross-cat lanes).
__global__ __launch_bounds__(256) void din_k1(
    const int* __restrict__ user_inputs,
    const int* __restrict__ record_inputs,
    const int* __restrict__ item_cat,
    const float* __restrict__ user_emb,
    const float* __restrict__ item_emb,
    const float* __restrict__ W1,
    const float* __restrict__ b1,
    const float* __restrict__ W2,
    const float* __restrict__ b2,
    int* __restrict__ srow_g,
    float* __restrict__ z_g,
    int* __restrict__ cstart_g)
{
  const int b = blockIdx.x;
  const int t = threadIdx.x;
  const int wave = t >> 6, lane = t & 63;

  __shared__ float4 w_lds[HH * 16 * CC];   // [j*16+i][c], 2304 float4 = 36.9 KB
  __shared__ float  w2_s[CC * HH];
  __shared__ float  u_s[DD];
  __shared__ float  pre_s[CC][HH];
  __shared__ int    wcnt[NW][CC];
  __shared__ int    cstart[CC + 1];
  __shared__ int    srow_sh[LL];

  // stage W1 e-half -> LDS, coalesced global reads, scattered LDS writes
  #pragma unroll
  for (int k = t; k < HH * 16 * CC; k += 256) {
    int c = k >> 8;            // k / 256
    int ji = k & 255;          // j*16 + i
    // src float4 index into W1: row (c*16 + j), e-half starts at float4 16
    int j = ji >> 4, i = ji & 15;
    w_lds[ji * CC + c] = ((const float4*)W1)[(size_t)(c * HH + j) * 32 + 16 + i];
  }
  if (t < CC * HH) w2_s[t] = W2[t];

  // loads + ballot counting
  int r = -1, c0 = -1;
  if (t < LL) {
    r = record_inputs[b * LL + t];
    if (r >= 0) c0 = item_cat[r];
  }
  if (t < DD) u_s[t] = user_emb[(size_t)user_inputs[b] * DD + t];

  int myrank = 0;
  #pragma unroll
  for (int c = 0; c < CC; ++c) {
    unsigned long long m = __ballot(c0 == c);
    if (lane == 0) wcnt[wave][c] = __popcll(m);
    if (c0 == c) myrank = __popcll(m & ((1ULL << lane) - 1ULL));
  }
  __syncthreads();

  if (t == 0) {
    int acc = 0;
    #pragma unroll
    for (int c = 0; c < CC; ++c) {
      cstart[c] = acc;
      acc += wcnt[0][c] + wcnt[1][c] + wcnt[2][c] + wcnt[3][c];
    }
    cstart[CC] = acc;
  }
  if (t < CC * HH) {   // pre = b1 + W1u . u
    int c = t / HH, j = t % HH;
    const float* wp = &W1[(size_t)(c * HH + j) * (2 * DD)];
    float acc = b1[c * HH + j];
    #pragma unroll 8
    for (int d = 0; d < DD; ++d) acc += wp[d] * u_s[d];
    pre_s[c][j] = acc;
  }
  __syncthreads();

  // stable scatter (to LDS + global for K2)
  if (c0 >= 0) {
    int off = cstart[c0];
    for (int w = 0; w < wave; ++w) off += wcnt[w][c0];
    int pos = off + myrank;
    srow_sh[pos] = r;
    srow_g[b * LL + pos] = r;
  }
  if (t < CC + 1) cstart_g[b * 10 + t] = cstart[t];
  __syncthreads();

  const int nvalid = cstart[CC];

  // per-item MLP score: e preloaded to regs, W from LDS, z = exp(s)
  if (t < nvalid) {
    int c = 0;
    #pragma unroll
    for (int q = 0; q < CC - 1; ++q) c += (t >= cstart[q + 1]) ? 1 : 0;
    int row = srow_sh[t];
    const float4* ep = (const float4*)&item_emb[(size_t)row * DD];

    float4 e[16];
    #pragma unroll
    for (int i = 0; i < 16; ++i) e[i] = ep[i];

    float acc[HH];
    #pragma unroll
    for (int j = 0; j < HH; ++j) acc[j] = pre_s[c][j];

    #pragma unroll
    for (int i = 0; i < 16; ++i) {
      float4 ev = e[i];
      #pragma unroll
      for (int j = 0; j < HH; ++j) {
        float4 wv = w_lds[(j * 16 + i) * CC + c];
        acc[j] += wv.x * ev.x + wv.y * ev.y + wv.z * ev.z + wv.w * ev.w;
      }
    }
    float s = b2[c];
    #pragma unroll
    for (int j = 0; j < HH; ++j) s += w2_s[c * HH + j] * fmaxf(acc[j], 0.f);
    z_g[b * LL + t] = expf(s);
  }
}

// K2: 9 waves per user (wave = category): gvec + top attention + output
__global__ __launch_bounds__(576) void din_k2(
    const int* __restrict__ user_inputs,
    const int* __restrict__ item_inputs,
    const float* __restrict__ user_emb,
    const float* __restrict__ item_emb,
    const float* __restrict__ Wt1,
    const float* __restrict__ bt1,
    const float* __restrict__ Wt2,
    const float* __restrict__ bt2,
    const int* __restrict__ srow_g,
    const float* __restrict__ z_g,
    const int* __restrict__ cstart_g,
    float* __restrict__ out)
{
  const int b = blockIdx.x;
  const int t = threadIdx.x;
  const int wave = t >> 6, lane = t & 63;   // wave == category

  __shared__ int   cstart_s[CC + 1];
  __shared__ float u_s[DD];
  __shared__ float gvec_s[CC][DD];
  __shared__ float h2_s[CC][HH];
  __shared__ float w2_s[CC];

  if (t < CC + 1) cstart_s[t] = cstart_g[b * 10 + t];
  if (t >= 64 && t < 128) u_s[t - 64] = user_emb[(size_t)user_inputs[b] * DD + (t - 64)];
  __syncthreads();

  // ---- per-wave: softmax-normalized weighted sum for category c = wave ----
  {
    const int c = wave;
    const int i0 = cstart_s[c], i1 = cstart_s[c + 1];
    const int base = b * LL;

    float zs = 0.f;
    for (int i = i0 + lane; i < i1; i += 64) zs += z_g[base + i];
    #pragma unroll
    for (int off = 32; off > 0; off >>= 1) zs += __shfl_xor(zs, off, 64);
    const float inv = 1.f / fmaxf(zs, 1e-30f);

    float acc = 0.f;
    if (i1 > i0) {
      int row = srow_g[base + i0];
      float ev = item_emb[(size_t)row * DD + lane];
      for (int i = i0; i < i1; ++i) {
        float ec = ev;
        if (i + 1 < i1) {               // prefetch next row
          int r2 = srow_g[base + i + 1];
          ev = item_emb[(size_t)r2 * DD + lane];
        }
        acc += z_g[base + i] * ec;
      }
    }
    gvec_s[c][lane] = acc * inv;        // empty cat -> 0
  }
  __syncthreads();

  // ---- top-level attention ----
  if (t < CC * HH) {
    int c = t / HH, j = t % HH;
    const float* wp = &Wt1[(size_t)j * (2 * DD)];
    float acc = bt1[j];
    #pragma unroll 8
    for (int d = 0; d < DD; ++d) acc += wp[d] * u_s[d];
    #pragma unroll 8
    for (int d = 0; d < DD; ++d) acc += wp[DD + d] * gvec_s[c][d];
    h2_s[c][j] = fmaxf(acc, 0.f);
  }
  __syncthreads();

  if (t == 0) {
    float s2[CC];
    float m = -INFINITY;
    #pragma unroll
    for (int c = 0; c < CC; ++c) {
      float acc = bt2[0];
      #pragma unroll
      for (int j = 0; j < HH; ++j) acc += Wt2[j] * h2_s[c][j];
      s2[c] = acc;
      if (cstart_s[c + 1] > cstart_s[c]) m = fmaxf(m, acc);
    }
    if (m == -INFINITY) m = 0.f;
    float sum = 0.f;
    float z2[CC];
    #pragma unroll
    for (int c = 0; c < CC; ++c) {
      z2[c] = (cstart_s[c + 1] > cstart_s[c]) ? expf(s2[c] - m) : 0.f;
      sum += z2[c];
    }
    float invs = 1.f / fmaxf(sum, 1e-30f);
    #pragma unroll
    for (int c = 0; c < CC; ++c) w2_s[c] = z2[c] * invs;
  }
  __syncthreads();

  if (t < DD) {
    float hy = 0.f;
    #pragma unroll
    for (int c = 0; c < CC; ++c) hy += w2_s[c] * gvec_s[c][t];
    float ti = item_emb[(size_t)item_inputs[b] * DD + t];
    float prod = hy * ti;
    #pragma unroll
    for (int off = 32; off > 0; off >>= 1)
      prod += __shfl_down(prod, off, 64);
    if (t == 0) out[b] = prod;
  }
}

extern "C" void kernel_launch(void* const* d_in, const int* in_sizes, int n_in,
                              void* d_out, int out_size, void* d_ws, size_t ws_size,
                              hipStream_t stream) {
  const int*   user_inputs   = (const int*)d_in[0];
  const int*   record_inputs = (const int*)d_in[1];
  const int*   item_inputs   = (const int*)d_in[2];
  const int*   item_cat      = (const int*)d_in[3];
  const float* user_emb      = (const float*)d_in[4];
  const float* item_emb      = (const float*)d_in[5];
  const float* W1            = (const float*)d_in[6];
  const float* b1            = (const float*)d_in[7];
  const float* W2            = (const float*)d_in[8];
  const float* b2            = (const float*)d_in[9];
  const float* Wt1           = (const float*)d_in[10];
  const float* bt1           = (const float*)d_in[11];
  const float* Wt2           = (const float*)d_in[12];
  const float* bt2           = (const float*)d_in[13];
  float* out = (float*)d_out;

  char* ws = (char*)d_ws;
  int*   srow_g   = (int*)(ws);                 // B*L ints
  float* z_g      = (float*)(ws + 1638400);     // B*L floats
  int*   cstart_g = (int*)(ws + 3276800);       // B*10 ints

  din_k1<<<NB, 256, 0, stream>>>(user_inputs, record_inputs, item_cat,
                                 user_emb, item_emb, W1, b1, W2, b2,
                                 srow_g, z_g, cstart_g);
  din_k2<<<NB, 576, 0, stream>>>(user_inputs, item_inputs, user_emb, item_emb,
                                 Wt1, bt1, Wt2, bt2,
                                 srow_g, z_g, cstart_g, out);
}

// Round 8
// 84.210 us; speedup vs baseline: 4.4838x; 1.3859x over previous
//
#include <hip/hip_runtime.h>
#include <math.h>

#define NB 2048
#define LL 200
#define DD 64
#define CC 9
#define HH 16
#define NW 4

// ---- d_ws layout (bytes) ----
// srow_g : int  [B*L]     @ 0          (1,638,400)
// z_g    : float[B*L]     @ 1,638,400  (1,638,400)   z = exp(s), M=0 softmax
// cstart : int  [B*10]    @ 3,276,800  (81,920)
// gvec   : float[B*C*D]   @ 3,358,720  (4,718,592)

// K1: per-user ballot sort + per-item MLP score -> z = exp(s)  (unchanged)
__global__ __launch_bounds__(256) void din_k1(
    const int* __restrict__ user_inputs,
    const int* __restrict__ record_inputs,
    const int* __restrict__ item_cat,
    const float* __restrict__ user_emb,
    const float* __restrict__ item_emb,
    const float* __restrict__ W1,
    const float* __restrict__ b1,
    const float* __restrict__ W2,
    const float* __restrict__ b2,
    int* __restrict__ srow_g,
    float* __restrict__ z_g,
    int* __restrict__ cstart_g)
{
  const int b = blockIdx.x;
  const int t = threadIdx.x;
  const int wave = t >> 6, lane = t & 63;

  __shared__ float4 w_lds[HH * 16 * CC];   // [j*16+i][c], 36.9 KB
  __shared__ float  w2_s[CC * HH];
  __shared__ float  u_s[DD];
  __shared__ float  pre_s[CC][HH];
  __shared__ int    wcnt[NW][CC];
  __shared__ int    cstart[CC + 1];
  __shared__ int    srow_sh[LL];

  #pragma unroll
  for (int k = t; k < HH * 16 * CC; k += 256) {
    int c = k >> 8;
    int ji = k & 255;
    int j = ji >> 4, i = ji & 15;
    w_lds[ji * CC + c] = ((const float4*)W1)[(size_t)(c * HH + j) * 32 + 16 + i];
  }
  if (t < CC * HH) w2_s[t] = W2[t];

  int r = -1, c0 = -1;
  if (t < LL) {
    r = record_inputs[b * LL + t];
    if (r >= 0) c0 = item_cat[r];
  }
  if (t < DD) u_s[t] = user_emb[(size_t)user_inputs[b] * DD + t];

  int myrank = 0;
  #pragma unroll
  for (int c = 0; c < CC; ++c) {
    unsigned long long m = __ballot(c0 == c);
    if (lane == 0) wcnt[wave][c] = __popcll(m);
    if (c0 == c) myrank = __popcll(m & ((1ULL << lane) - 1ULL));
  }
  __syncthreads();

  if (t == 0) {
    int acc = 0;
    #pragma unroll
    for (int c = 0; c < CC; ++c) {
      cstart[c] = acc;
      acc += wcnt[0][c] + wcnt[1][c] + wcnt[2][c] + wcnt[3][c];
    }
    cstart[CC] = acc;
  }
  if (t < CC * HH) {   // pre = b1 + W1u . u
    int c = t / HH, j = t % HH;
    const float* wp = &W1[(size_t)(c * HH + j) * (2 * DD)];
    float acc = b1[c * HH + j];
    #pragma unroll 8
    for (int d = 0; d < DD; ++d) acc += wp[d] * u_s[d];
    pre_s[c][j] = acc;
  }
  __syncthreads();

  if (c0 >= 0) {
    int off = cstart[c0];
    for (int w = 0; w < wave; ++w) off += wcnt[w][c0];
    int pos = off + myrank;
    srow_sh[pos] = r;
    srow_g[b * LL + pos] = r;
  }
  if (t < CC + 1) cstart_g[b * 10 + t] = cstart[t];
  __syncthreads();

  const int nvalid = cstart[CC];

  if (t < nvalid) {
    int c = 0;
    #pragma unroll
    for (int q = 0; q < CC - 1; ++q) c += (t >= cstart[q + 1]) ? 1 : 0;
    int row = srow_sh[t];
    const float4* ep = (const float4*)&item_emb[(size_t)row * DD];

    float4 e[16];
    #pragma unroll
    for (int i = 0; i < 16; ++i) e[i] = ep[i];

    float acc[HH];
    #pragma unroll
    for (int j = 0; j < HH; ++j) acc[j] = pre_s[c][j];

    #pragma unroll
    for (int i = 0; i < 16; ++i) {
      float4 ev = e[i];
      #pragma unroll
      for (int j = 0; j < HH; ++j) {
        float4 wv = w_lds[(j * 16 + i) * CC + c];
        acc[j] += wv.x * ev.x + wv.y * ev.y + wv.z * ev.z + wv.w * ev.w;
      }
    }
    float s = b2[c];
    #pragma unroll
    for (int j = 0; j < HH; ++j) s += w2_s[c * HH + j] * fmaxf(acc[j], 0.f);
    z_g[b * LL + t] = expf(s);
  }
}

// KC: one wave per (b,c) pair, 4 pairs per block, barrier-free.
// srow/z pulled into lane regs once; e-rows 4-deep ILP.
__global__ __launch_bounds__(256) void din_kc(
    const float* __restrict__ item_emb,
    const int* __restrict__ srow_g,
    const float* __restrict__ z_g,
    const int* __restrict__ cstart_g,
    float* __restrict__ gvec_g)
{
  const int pair = blockIdx.x * NW + (threadIdx.x >> 6);   // [0, B*C)
  const int lane = threadIdx.x & 63;
  const int b = pair / CC;
  const int c = pair - b * CC;
  const int base = b * LL;

  const int i0 = cstart_g[b * 10 + c];
  const int i1 = cstart_g[b * 10 + c + 1];

  float acc = 0.f;
  float zs = 0.f;

  for (int cb = i0; cb < i1; cb += 64) {
    const int nn = min(64, i1 - cb);
    const bool ok = (cb + lane < i1);
    int   rv = ok ? srow_g[base + cb + lane] : 0;
    float zv = ok ? z_g[base + cb + lane]    : 0.f;
    zs += zv;

    int k = 0;
    for (; k + 4 <= nn; k += 4) {
      int   r0 = __shfl(rv, k, 64),     r1 = __shfl(rv, k + 1, 64);
      int   r2 = __shfl(rv, k + 2, 64), r3 = __shfl(rv, k + 3, 64);
      float z0 = __shfl(zv, k, 64),     z1 = __shfl(zv, k + 1, 64);
      float z2 = __shfl(zv, k + 2, 64), z3 = __shfl(zv, k + 3, 64);
      float e0 = item_emb[(size_t)r0 * DD + lane];
      float e1 = item_emb[(size_t)r1 * DD + lane];
      float e2 = item_emb[(size_t)r2 * DD + lane];
      float e3 = item_emb[(size_t)r3 * DD + lane];
      acc += z0 * e0; acc += z1 * e1; acc += z2 * e2; acc += z3 * e3;
    }
    for (; k < nn; ++k) {
      int   rr = __shfl(rv, k, 64);
      float zz = __shfl(zv, k, 64);
      acc += zz * item_emb[(size_t)rr * DD + lane];
    }
  }

  // wave-sum of z (deterministic tree)
  #pragma unroll
  for (int off = 32; off > 0; off >>= 1) zs += __shfl_xor(zs, off, 64);
  const float inv = 1.f / fmaxf(zs, 1e-30f);

  gvec_g[(size_t)pair * DD + lane] = acc * inv;   // empty cat -> 0
}

// KD: per-user top-level attention + output
__global__ __launch_bounds__(256) void din_kd(
    const int* __restrict__ user_inputs,
    const int* __restrict__ item_inputs,
    const float* __restrict__ user_emb,
    const float* __restrict__ item_emb,
    const float* __restrict__ Wt1,
    const float* __restrict__ bt1,
    const float* __restrict__ Wt2,
    const float* __restrict__ bt2,
    const int* __restrict__ cstart_g,
    const float* __restrict__ gvec_g,
    float* __restrict__ out)
{
  const int b = blockIdx.x;
  const int t = threadIdx.x;

  __shared__ float u_s[DD];
  __shared__ float g_s[CC * DD];
  __shared__ float h2_s[CC][HH];
  __shared__ float w2_s[CC];
  __shared__ int   cnt_s[CC];

  if (t < DD) u_s[t] = user_emb[(size_t)user_inputs[b] * DD + t];
  for (int x = t; x < CC * DD; x += 256) g_s[x] = gvec_g[(size_t)b * CC * DD + x];
  if (t < CC) cnt_s[t] = cstart_g[b * 10 + t + 1] - cstart_g[b * 10 + t];
  __syncthreads();

  if (t < CC * HH) {
    int c = t / HH, j = t % HH;
    const float* wp = &Wt1[(size_t)j * (2 * DD)];
    float acc = bt1[j];
    #pragma unroll 8
    for (int d = 0; d < DD; ++d) acc += wp[d] * u_s[d];
    #pragma unroll 8
    for (int d = 0; d < DD; ++d) acc += wp[DD + d] * g_s[c * DD + d];
    h2_s[c][j] = fmaxf(acc, 0.f);
  }
  __syncthreads();

  if (t == 0) {
    float s2[CC];
    float m = -INFINITY;
    #pragma unroll
    for (int c = 0; c < CC; ++c) {
      float acc = bt2[0];
      #pragma unroll
      for (int j = 0; j < HH; ++j) acc += Wt2[j] * h2_s[c][j];
      s2[c] = acc;
      if (cnt_s[c] > 0) m = fmaxf(m, acc);
    }
    if (m == -INFINITY) m = 0.f;
    float sum = 0.f;
    float z2[CC];
    #pragma unroll
    for (int c = 0; c < CC; ++c) {
      z2[c] = (cnt_s[c] > 0) ? expf(s2[c] - m) : 0.f;
      sum += z2[c];
    }
    float inv = 1.f / fmaxf(sum, 1e-30f);
    #pragma unroll
    for (int c = 0; c < CC; ++c) w2_s[c] = z2[c] * inv;
  }
  __syncthreads();

  if (t < DD) {
    float hy = 0.f;
    #pragma unroll
    for (int c = 0; c < CC; ++c) hy += w2_s[c] * g_s[c * DD + t];
    float ti = item_emb[(size_t)item_inputs[b] * DD + t];
    float prod = hy * ti;
    #pragma unroll
    for (int off = 32; off > 0; off >>= 1)
      prod += __shfl_down(prod, off, 64);
    if (t == 0) out[b] = prod;
  }
}

extern "C" void kernel_launch(void* const* d_in, const int* in_sizes, int n_in,
                              void* d_out, int out_size, void* d_ws, size_t ws_size,
                              hipStream_t stream) {
  const int*   user_inputs   = (const int*)d_in[0];
  const int*   record_inputs = (const int*)d_in[1];
  const int*   item_inputs   = (const int*)d_in[2];
  const int*   item_cat      = (const int*)d_in[3];
  const float* user_emb      = (const float*)d_in[4];
  const float* item_emb      = (const float*)d_in[5];
  const float* W1            = (const float*)d_in[6];
  const float* b1            = (const float*)d_in[7];
  const float* W2            = (const float*)d_in[8];
  const float* b2            = (const float*)d_in[9];
  const float* Wt1           = (const float*)d_in[10];
  const float* bt1           = (const float*)d_in[11];
  const float* Wt2           = (const float*)d_in[12];
  const float* bt2           = (const float*)d_in[13];
  float* out = (float*)d_out;

  char* ws = (char*)d_ws;
  int*   srow_g   = (int*)(ws);                 // B*L ints
  float* z_g      = (float*)(ws + 1638400);     // B*L floats
  int*   cstart_g = (int*)(ws + 3276800);       // B*10 ints
  float* gvec_g   = (float*)(ws + 3358720);     // B*C*D floats

  din_k1<<<NB, 256, 0, stream>>>(user_inputs, record_inputs, item_cat,
                                 user_emb, item_emb, W1, b1, W2, b2,
                                 srow_g, z_g, cstart_g);
  din_kc<<<(NB * CC) / NW, 256, 0, stream>>>(item_emb, srow_g, z_g, cstart_g, gvec_g);
  din_kd<<<NB, 256, 0, stream>>>(user_inputs, item_inputs, user_emb, item_emb,
                                 Wt1, bt1, Wt2, bt2, cstart_g, gvec_g, out);
}